// Round 4
// baseline (452.347 us; speedup 1.0000x reference)
//
#include <hip/hip_runtime.h>
#include <hip/hip_bf16.h>
#include <stdint.h>

// Problem constants (fixed by the reference)
#define HD      4096            // K (hidden)
#define MROWS   8192            // B*S
#define NQ      4096
#define NKV     1024
#define NTOT    6144            // NQ + 2*NKV
#define RMS_EPS 1e-6f

typedef __attribute__((ext_vector_type(8))) short bf16x8;
typedef __attribute__((ext_vector_type(16))) float f32x16;

static __device__ __forceinline__ unsigned short f2bf(float f) {
  union { float f; unsigned u; } a; a.f = f;
  unsigned r = a.u + 0x7FFFu + ((a.u >> 16) & 1u);   // RNE
  return (unsigned short)(r >> 16);
}

// ---------------- RMSNorm + cast to bf16 ----------------
__global__ __launch_bounds__(256) void rmsnorm_cast_kernel(
    const float* __restrict__ x, const float* __restrict__ gamma,
    unsigned short* __restrict__ xn) {
  const int row = blockIdx.x;                 // 8192 rows
  const float4* xr = (const float4*)(x + (size_t)row * HD);
  const float4* g4 = (const float4*)gamma;
  const int t = threadIdx.x;                  // 256 threads
  float4 v[4];
  float ss = 0.f;
#pragma unroll
  for (int i = 0; i < 4; ++i) {
    v[i] = xr[t + i * 256];
    ss += v[i].x * v[i].x + v[i].y * v[i].y + v[i].z * v[i].z + v[i].w * v[i].w;
  }
#pragma unroll
  for (int o = 32; o > 0; o >>= 1) ss += __shfl_xor(ss, o, 64);
  __shared__ float red[4];
  if ((t & 63) == 0) red[t >> 6] = ss;
  __syncthreads();
  const float tot = red[0] + red[1] + red[2] + red[3];
  const float rstd = rsqrtf(tot * (1.f / HD) + RMS_EPS);
  ushort4* xo = (ushort4*)(xn + (size_t)row * HD);
#pragma unroll
  for (int i = 0; i < 4; ++i) {
    const float4 g = g4[t + i * 256];
    ushort4 o;
    o.x = f2bf(v[i].x * rstd * g.x);
    o.y = f2bf(v[i].y * rstd * g.y);
    o.z = f2bf(v[i].z * rstd * g.z);
    o.w = f2bf(v[i].w * rstd * g.w);
    xo[t + i * 256] = o;
  }
}

// ---------------- Transpose + cast W[K][Nw] f32 -> Wt[Nw][K] bf16 ----------------
__global__ __launch_bounds__(256) void transpose_cast_kernel(
    const float* __restrict__ w, unsigned short* __restrict__ wt, int Nw) {
  __shared__ float tile[32][33];
  const int kt = blockIdx.y;                  // K/32
  const int nb = blockIdx.x;                  // Nw/32
  const int t = threadIdx.x;
  const int r = t >> 3, c4 = t & 7;
  const float4 vin = *(const float4*)&w[(size_t)(kt * 32 + r) * Nw + nb * 32 + c4 * 4];
  tile[r][c4 * 4 + 0] = vin.x;
  tile[r][c4 * 4 + 1] = vin.y;
  tile[r][c4 * 4 + 2] = vin.z;
  tile[r][c4 * 4 + 3] = vin.w;
  __syncthreads();
  ushort4 o;
  o.x = f2bf(tile[c4 * 4 + 0][r]);
  o.y = f2bf(tile[c4 * 4 + 1][r]);
  o.z = f2bf(tile[c4 * 4 + 2][r]);
  o.w = f2bf(tile[c4 * 4 + 3][r]);
  *(ushort4*)&wt[(size_t)(nb * 32 + r) * HD + kt * 32 + c4 * 4] = o;
}

// ---------------- 256x256 8-phase bf16 GEMM, 32x32x16 MFMA, Gray quadrants ----
// C[M,N] = A[M,K] * Bt[N,K]^T ; M=8192, N=6144, K=4096. BK=64, 512 thr.

static __device__ __forceinline__ void gload_lds16(const unsigned short* g,
                                                   unsigned short* l) {
  __builtin_amdgcn_global_load_lds(
      (const __attribute__((address_space(1))) void*)g,
      (__attribute__((address_space(3))) void*)l, 16, 0, 0);
}

#define VM4 asm volatile("s_waitcnt vmcnt(4)" ::: "memory")
#define VM0 asm volatile("s_waitcnt vmcnt(0)" ::: "memory")
#define VMNONE ((void)0)

// ds-read the 8 A fragments (2 m-blocks x 4 ks) of row-half HA
#define RD_A(BUF, HA)                                                          \
  do {                                                                         \
    const char* Ah = (const char*)&lds[0][BUF][HA][0];                         \
    _Pragma("unroll") for (int mi = 0; mi < 2; ++mi)                           \
      _Pragma("unroll") for (int ks = 0; ks < 4; ++ks)                         \
        af[mi][ks] = *(const bf16x8*)(Ah + (wr * 64 + mi * 32 + r32) * 128 +   \
                                      (((ks * 2 + hi) ^ swx) << 4));           \
  } while (0)

// ds-read the 4 B fragments (1 n-block x 4 ks) of col-half HB
#define RD_B(BUF, HB)                                                          \
  do {                                                                         \
    const char* Bh = (const char*)&lds[1][BUF][HB][0];                         \
    _Pragma("unroll") for (int ks = 0; ks < 4; ++ks)                           \
      bfr[ks] = *(const bf16x8*)(Bh + (wc * 32 + r32) * 128 +                  \
                                 (((ks * 2 + hi) ^ swx) << 4));                \
  } while (0)

// barrier -> 8 MFMA (quadrant HA x HB over K=64) under setprio -> VM -> barrier
#define MMA(HA, HB, VM)                                                        \
  do {                                                                         \
    __builtin_amdgcn_s_barrier();                                              \
    __builtin_amdgcn_s_setprio(1);                                             \
    _Pragma("unroll") for (int ks = 0; ks < 4; ++ks)                           \
      _Pragma("unroll") for (int mi = 0; mi < 2; ++mi)                         \
        acc[(HA) * 2 + mi][HB] = __builtin_amdgcn_mfma_f32_32x32x16_bf16(      \
            af[mi][ks], bfr[ks], acc[(HA) * 2 + mi][HB], 0, 0, 0);             \
    __builtin_amdgcn_s_setprio(0);                                             \
    VM;                                                                        \
    __builtin_amdgcn_s_barrier();                                              \
  } while (0)

__global__ __launch_bounds__(512, 2) void gemm_qkv_kernel(
    const unsigned short* __restrict__ A,    // [MROWS][HD] bf16 (xn)
    const unsigned short* __restrict__ Bt,   // [NTOT][HD] bf16 (w^T)
    float* __restrict__ out) {
  // [mat A/B][buf][row-half][128 rows x 64 k] bf16 = 128 KiB total
  __shared__ unsigned short lds[2][2][2][8192] __attribute__((aligned(16)));

  // XCD-rectangular swizzle: grid 32mt x 24nt = 768 blocks, XCD = bid&7.
  const int bid = blockIdx.x;
  const int xcd = bid & 7;
  const int idx = bid >> 3;                  // 0..95
  const int sr  = idx >> 5;                  // sub-round 0..2
  const int i32 = idx & 31;
  const int mt  = (xcd >> 1) * 8 + (i32 >> 2);
  const int nt  = (xcd & 1) * 12 + sr * 4 + (i32 & 3);
  const int m0 = mt * 256, n0 = nt * 256;

  const int tid = threadIdx.x;
  const int w = tid >> 6, lane = tid & 63;
  const int wr = w >> 2, wc = w & 3;         // 2 x 4 waves, each 128x64 out
  const int r32 = lane & 31, hi = lane >> 5; // 32x32 fragment coords
  const int swx = (r32 >> 2) & 7;            // bank swizzle field

  // staging: linear LDS dest, inverse-swizzled global source (rule #21)
  const int wslot = w * 512;                 // wave-uniform LDS element base
  const int r3 = tid >> 3;                   // row 0..63 within pass
  const int scolb = (((tid & 7) ^ ((r3 >> 2) & 7))) << 4;
  const size_t so0 = (size_t)r3 * HD + (scolb >> 1);
  const size_t so1 = so0 + (size_t)64 * HD;

  const unsigned short* const Ab0 = A + (size_t)m0 * HD;
  const unsigned short* const Ab1 = Ab0 + (size_t)128 * HD;
  const unsigned short* const Bb0 = Bt + (size_t)n0 * HD;
  const unsigned short* const Bb1 = Bb0 + (size_t)128 * HD;

  auto STG = [&](const unsigned short* g, unsigned short* l) {
    gload_lds16(g + so0, l + wslot);
    gload_lds16(g + so1, l + 4096 + wslot);
  };

  f32x16 acc[4][2];
#pragma unroll
  for (int i = 0; i < 4; ++i)
#pragma unroll
    for (int j = 0; j < 2; ++j) acc[i][j] = (f32x16)(0.f);

  bf16x8 af[2][4];
  bf16x8 bfr[4];

  // prologue: tile0 -> buf0 (4 halves), tile1 A0/B0 -> buf1
  STG(Ab0, &lds[0][0][0][0]);
  STG(Bb0, &lds[1][0][0][0]);
  STG(Ab1, &lds[0][0][1][0]);
  STG(Bb1, &lds[1][0][1][0]);
  STG(Ab0 + 64, &lds[0][1][0][0]);
  STG(Bb0 + 64, &lds[1][1][0][0]);
  VM4;                                       // tile0's 8 loads landed
  __builtin_amdgcn_s_barrier();

  // 64 K-tiles, 2 per cycle; quadrant order (0,1),(0,0),(1,0),(1,1).
  // Stage slots chosen so each LDS region is overwritten strictly after its
  // last ds_read phase; VM4 at p3/p7 retires every load before its first read.
  for (int t = 0; t < 31; ++t) {
    const size_t k1 = (size_t)(2 * t + 1) * 64;
    const size_t o2 = (size_t)(2 * t + 2) * 64;
    const size_t o3 = (size_t)(2 * t + 3) * 64;
    // ---- buf0 (tile 2t) ----
    RD_A(0, 0); RD_B(0, 1); STG(Bb1 + k1, &lds[1][1][1][0]); MMA(0, 1, VMNONE); // p0
    RD_B(0, 0);             STG(Ab1 + k1, &lds[0][1][1][0]); MMA(0, 0, VMNONE); // p1
    RD_A(0, 1);             STG(Bb0 + o2, &lds[1][0][0][0]); MMA(1, 0, VMNONE); // p2
    RD_B(0, 1);             STG(Ab1 + o2, &lds[0][0][1][0]); MMA(1, 1, VM4);    // p3
    // ---- buf1 (tile 2t+1) ----
    RD_A(1, 0); RD_B(1, 1); STG(Ab0 + o2, &lds[0][0][0][0]); MMA(0, 1, VMNONE); // p4
    RD_B(1, 0);             STG(Bb1 + o2, &lds[1][0][1][0]); MMA(0, 0, VMNONE); // p5
    RD_A(1, 1);             STG(Ab0 + o3, &lds[0][1][0][0]); MMA(1, 0, VMNONE); // p6
    RD_B(1, 1);             STG(Bb0 + o3, &lds[1][1][0][0]); MMA(1, 1, VM4);    // p7
  }
  {                                          // t = 31: tiles 62 (b0), 63 (b1)
    const size_t k1 = (size_t)63 * 64;
    RD_A(0, 0); RD_B(0, 1); STG(Bb1 + k1, &lds[1][1][1][0]); MMA(0, 1, VMNONE);
    RD_B(0, 0);             STG(Ab1 + k1, &lds[0][1][1][0]); MMA(0, 0, VMNONE);
    RD_A(0, 1);                                              MMA(1, 0, VMNONE);
    RD_B(0, 1);                                              MMA(1, 1, VM0);
    RD_A(1, 0); RD_B(1, 1);                                  MMA(0, 1, VMNONE);
    RD_B(1, 0);                                              MMA(0, 0, VMNONE);
    RD_A(1, 1);                                              MMA(1, 0, VMNONE);
    RD_B(1, 1);                                              MMA(1, 1, VMNONE);
  }

  // epilogue: route this block's 256 columns to q / k / v region
  size_t obase; int ldc, nc;
  if (n0 < NQ)            { obase = 0;                                        ldc = NQ;  nc = n0; }
  else if (n0 < NQ + NKV) { obase = (size_t)MROWS * NQ;                       ldc = NKV; nc = n0 - NQ; }
  else                    { obase = (size_t)MROWS * NQ + (size_t)MROWS * NKV; ldc = NKV; nc = n0 - NQ - NKV; }

  // C/D layout (verified m74/m101): col = lane&31, row = (reg&3)+8*(reg>>2)+4*hi
#pragma unroll
  for (int I = 0; I < 4; ++I) {
    const int rbase = m0 + (I >> 1) * 128 + wr * 64 + (I & 1) * 32 + hi * 4;
#pragma unroll
    for (int J = 0; J < 2; ++J) {
      const int col = nc + J * 128 + wc * 32 + r32;
#pragma unroll
      for (int reg = 0; reg < 16; ++reg) {
        const int row = rbase + (reg & 3) + 8 * (reg >> 2);
        out[obase + (size_t)row * ldc + col] = acc[I][J][reg];
      }
    }
  }
}

extern "C" void kernel_launch(void* const* d_in, const int* in_sizes, int n_in,
                              void* d_out, int out_size, void* d_ws, size_t ws_size,
                              hipStream_t stream) {
  const float* x     = (const float*)d_in[0];
  const float* gamma = (const float*)d_in[1];
  const float* wq    = (const float*)d_in[2];
  const float* wk    = (const float*)d_in[3];
  const float* wv    = (const float*)d_in[4];
  float* out = (float*)d_out;

  // workspace layout: xn bf16 [8192][4096] then wt bf16 [6144][4096]
  unsigned short* xn = (unsigned short*)d_ws;
  unsigned short* wt = xn + (size_t)MROWS * HD;

  rmsnorm_cast_kernel<<<MROWS, 256, 0, stream>>>(x, gamma, xn);
  transpose_cast_kernel<<<dim3(NQ / 32, HD / 32), 256, 0, stream>>>(wq, wt, NQ);
  transpose_cast_kernel<<<dim3(NKV / 32, HD / 32), 256, 0, stream>>>(
      wk, wt + (size_t)NQ * HD, NKV);
  transpose_cast_kernel<<<dim3(NKV / 32, HD / 32), 256, 0, stream>>>(
      wv, wt + (size_t)(NQ + NKV) * HD, NKV);
  gemm_qkv_kernel<<<(MROWS / 256) * (NTOT / 256), 512, 0, stream>>>(xn, wt, out);
}

// Round 5
// 430.559 us; speedup vs baseline: 1.0506x; 1.0506x over previous
//
#include <hip/hip_runtime.h>
#include <hip/hip_bf16.h>
#include <stdint.h>

// Problem constants (fixed by the reference)
#define HD      4096            // K (hidden)
#define MROWS   8192            // B*S
#define NQ      4096
#define NKV     1024
#define NTOT    6144            // NQ + 2*NKV
#define RMS_EPS 1e-6f

typedef __attribute__((ext_vector_type(8))) short bf16x8;
typedef __attribute__((ext_vector_type(16))) float f32x16;

static __device__ __forceinline__ unsigned short f2bf(float f) {
  union { float f; unsigned u; } a; a.f = f;
  unsigned r = a.u + 0x7FFFu + ((a.u >> 16) & 1u);   // RNE
  return (unsigned short)(r >> 16);
}

// ---------------- RMSNorm + cast to bf16 ----------------
__global__ __launch_bounds__(256) void rmsnorm_cast_kernel(
    const float* __restrict__ x, const float* __restrict__ gamma,
    unsigned short* __restrict__ xn) {
  const int row = blockIdx.x;                 // 8192 rows
  const float4* xr = (const float4*)(x + (size_t)row * HD);
  const float4* g4 = (const float4*)gamma;
  const int t = threadIdx.x;                  // 256 threads
  float4 v[4];
  float ss = 0.f;
#pragma unroll
  for (int i = 0; i < 4; ++i) {
    v[i] = xr[t + i * 256];
    ss += v[i].x * v[i].x + v[i].y * v[i].y + v[i].z * v[i].z + v[i].w * v[i].w;
  }
#pragma unroll
  for (int o = 32; o > 0; o >>= 1) ss += __shfl_xor(ss, o, 64);
  __shared__ float red[4];
  if ((t & 63) == 0) red[t >> 6] = ss;
  __syncthreads();
  const float tot = red[0] + red[1] + red[2] + red[3];
  const float rstd = rsqrtf(tot * (1.f / HD) + RMS_EPS);
  ushort4* xo = (ushort4*)(xn + (size_t)row * HD);
#pragma unroll
  for (int i = 0; i < 4; ++i) {
    const float4 g = g4[t + i * 256];
    ushort4 o;
    o.x = f2bf(v[i].x * rstd * g.x);
    o.y = f2bf(v[i].y * rstd * g.y);
    o.z = f2bf(v[i].z * rstd * g.z);
    o.w = f2bf(v[i].w * rstd * g.w);
    xo[t + i * 256] = o;
  }
}

// ---------------- Transpose + cast W[K][Nw] f32 -> Wt[Nw][K] bf16 ----------------
__global__ __launch_bounds__(256) void transpose_cast_kernel(
    const float* __restrict__ w, unsigned short* __restrict__ wt, int Nw) {
  __shared__ float tile[32][33];
  const int kt = blockIdx.y;                  // K/32
  const int nb = blockIdx.x;                  // Nw/32
  const int t = threadIdx.x;
  const int r = t >> 3, c4 = t & 7;
  const float4 vin = *(const float4*)&w[(size_t)(kt * 32 + r) * Nw + nb * 32 + c4 * 4];
  tile[r][c4 * 4 + 0] = vin.x;
  tile[r][c4 * 4 + 1] = vin.y;
  tile[r][c4 * 4 + 2] = vin.z;
  tile[r][c4 * 4 + 3] = vin.w;
  __syncthreads();
  ushort4 o;
  o.x = f2bf(tile[c4 * 4 + 0][r]);
  o.y = f2bf(tile[c4 * 4 + 1][r]);
  o.z = f2bf(tile[c4 * 4 + 2][r]);
  o.w = f2bf(tile[c4 * 4 + 3][r]);
  *(ushort4*)&wt[(size_t)(nb * 32 + r) * HD + kt * 32 + c4 * 4] = o;
}

// ---------------- 256x256 8-phase bf16 GEMM, 32x32x16 MFMA, Gray quadrants ----
// C[M,N] = A[M,K] * Bt[N,K]^T ; M=8192, N=6144, K=4096. BK=64, 512 thr.

static __device__ __forceinline__ void gload_lds16(const unsigned short* g,
                                                   unsigned short* l) {
  __builtin_amdgcn_global_load_lds(
      (const __attribute__((address_space(1))) void*)g,
      (__attribute__((address_space(3))) void*)l, 16, 0, 0);
}

#define VM4 asm volatile("s_waitcnt vmcnt(4)" ::: "memory")
#define VM0 asm volatile("s_waitcnt vmcnt(0)" ::: "memory")
#define VMNONE ((void)0)

// ds-read the 8 A fragments (2 m-blocks x 4 ks) of row-half HA
#define RD_A(BUF, HA)                                                          \
  do {                                                                         \
    const char* Ah = (const char*)&lds[0][BUF][HA][0];                         \
    _Pragma("unroll") for (int mi = 0; mi < 2; ++mi)                           \
      _Pragma("unroll") for (int ks = 0; ks < 4; ++ks)                         \
        af[mi][ks] = *(const bf16x8*)(Ah + (wr * 64 + mi * 32 + r32) * 128 +   \
                                      (((ks * 2 + hi) ^ swx) << 4));           \
  } while (0)

// ds-read the 4 B fragments (1 n-block x 4 ks) of col-half HB
#define RD_B(BUF, HB)                                                          \
  do {                                                                         \
    const char* Bh = (const char*)&lds[1][BUF][HB][0];                         \
    _Pragma("unroll") for (int ks = 0; ks < 4; ++ks)                           \
      bfr[ks] = *(const bf16x8*)(Bh + (wc * 32 + r32) * 128 +                  \
                                 (((ks * 2 + hi) ^ swx) << 4));                \
  } while (0)

// barrier -> 8 MFMA (quadrant HA x HB over K=64) under setprio -> VM -> barrier
#define MMA(HA, HB, VM)                                                        \
  do {                                                                         \
    __builtin_amdgcn_s_barrier();                                              \
    __builtin_amdgcn_s_setprio(1);                                             \
    _Pragma("unroll") for (int ks = 0; ks < 4; ++ks)                           \
      _Pragma("unroll") for (int mi = 0; mi < 2; ++mi)                         \
        acc[(HA) * 2 + mi][HB] = __builtin_amdgcn_mfma_f32_32x32x16_bf16(      \
            af[mi][ks], bfr[ks], acc[(HA) * 2 + mi][HB], 0, 0, 0);             \
    __builtin_amdgcn_s_setprio(0);                                             \
    VM;                                                                        \
    __builtin_amdgcn_s_barrier();                                              \
  } while (0)

__global__ __launch_bounds__(512, 2) void gemm_qkv_kernel(
    const unsigned short* __restrict__ A,    // [MROWS][HD] bf16 (xn)
    const unsigned short* __restrict__ Bt,   // [NTOT][HD] bf16 (w^T)
    float* __restrict__ out) {
  // [mat A/B][buf][row-half][128 rows x 64 k] bf16 = 128 KiB total
  __shared__ unsigned short lds[2][2][2][8192] __attribute__((aligned(16)));

  // XCD-rectangular swizzle: grid 32mt x 24nt = 768 blocks, XCD = bid&7.
  const int bid = blockIdx.x;
  const int xcd = bid & 7;
  const int idx = bid >> 3;                  // 0..95
  const int sr  = idx >> 5;                  // sub-round 0..2
  const int i32 = idx & 31;
  const int mt  = (xcd >> 1) * 8 + (i32 >> 2);
  const int nt  = (xcd & 1) * 12 + sr * 4 + (i32 & 3);
  const int m0 = mt * 256, n0 = nt * 256;

  const int tid = threadIdx.x;
  const int w = tid >> 6, lane = tid & 63;
  const int wr = w >> 2, wc = w & 3;         // 2 x 4 waves, each 128x64 out
  const int r32 = lane & 31, hi = lane >> 5; // 32x32 fragment coords
  const int swx = (r32 >> 1) & 7;            // bank swizzle field: 8 values per
                                             // 16-lane quarter (2 lanes each)

  // staging: linear LDS dest, inverse-swizzled global source (rule #21)
  const int wslot = w * 512;                 // wave-uniform LDS element base
  const int r3 = tid >> 3;                   // row 0..63 within pass
  const int scolb = (((tid & 7) ^ ((r3 >> 1) & 7))) << 4;
  const size_t so0 = (size_t)r3 * HD + (scolb >> 1);
  const size_t so1 = so0 + (size_t)64 * HD;

  const unsigned short* const Ab0 = A + (size_t)m0 * HD;
  const unsigned short* const Ab1 = Ab0 + (size_t)128 * HD;
  const unsigned short* const Bb0 = Bt + (size_t)n0 * HD;
  const unsigned short* const Bb1 = Bb0 + (size_t)128 * HD;

  auto STG = [&](const unsigned short* g, unsigned short* l) {
    gload_lds16(g + so0, l + wslot);
    gload_lds16(g + so1, l + 4096 + wslot);
  };

  f32x16 acc[4][2];
#pragma unroll
  for (int i = 0; i < 4; ++i)
#pragma unroll
    for (int j = 0; j < 2; ++j) acc[i][j] = (f32x16)(0.f);

  bf16x8 af[2][4];
  bf16x8 bfr[4];

  // prologue: tile0 -> buf0 (4 halves), tile1 A0/B0 -> buf1
  STG(Ab0, &lds[0][0][0][0]);
  STG(Bb0, &lds[1][0][0][0]);
  STG(Ab1, &lds[0][0][1][0]);
  STG(Bb1, &lds[1][0][1][0]);
  STG(Ab0 + 64, &lds[0][1][0][0]);
  STG(Bb0 + 64, &lds[1][1][0][0]);
  VM4;                                       // tile0's 8 loads landed
  __builtin_amdgcn_s_barrier();

  // 64 K-tiles, 2 per cycle; quadrant order (0,1),(0,0),(1,0),(1,1).
  // Stage slots chosen so each LDS region is overwritten strictly after its
  // last ds_read phase; VM4 at p3/p7 retires every load before its first read.
  for (int t = 0; t < 31; ++t) {
    const size_t k1 = (size_t)(2 * t + 1) * 64;
    const size_t o2 = (size_t)(2 * t + 2) * 64;
    const size_t o3 = (size_t)(2 * t + 3) * 64;
    // ---- buf0 (tile 2t) ----
    RD_A(0, 0); RD_B(0, 1); STG(Bb1 + k1, &lds[1][1][1][0]); MMA(0, 1, VMNONE); // p0
    RD_B(0, 0);             STG(Ab1 + k1, &lds[0][1][1][0]); MMA(0, 0, VMNONE); // p1
    RD_A(0, 1);             STG(Bb0 + o2, &lds[1][0][0][0]); MMA(1, 0, VMNONE); // p2
    RD_B(0, 1);             STG(Ab1 + o2, &lds[0][0][1][0]); MMA(1, 1, VM4);    // p3
    // ---- buf1 (tile 2t+1) ----
    RD_A(1, 0); RD_B(1, 1); STG(Ab0 + o2, &lds[0][0][0][0]); MMA(0, 1, VMNONE); // p4
    RD_B(1, 0);             STG(Bb1 + o2, &lds[1][0][1][0]); MMA(0, 0, VMNONE); // p5
    RD_A(1, 1);             STG(Ab0 + o3, &lds[0][1][0][0]); MMA(1, 0, VMNONE); // p6
    RD_B(1, 1);             STG(Bb0 + o3, &lds[1][1][0][0]); MMA(1, 1, VM4);    // p7
  }
  {                                          // t = 31: tiles 62 (b0), 63 (b1)
    const size_t k1 = (size_t)63 * 64;
    RD_A(0, 0); RD_B(0, 1); STG(Bb1 + k1, &lds[1][1][1][0]); MMA(0, 1, VMNONE);
    RD_B(0, 0);             STG(Ab1 + k1, &lds[0][1][1][0]); MMA(0, 0, VMNONE);
    RD_A(0, 1);                                              MMA(1, 0, VMNONE);
    RD_B(0, 1);                                              MMA(1, 1, VM0);
    RD_A(1, 0); RD_B(1, 1);                                  MMA(0, 1, VMNONE);
    RD_B(1, 0);                                              MMA(0, 0, VMNONE);
    RD_A(1, 1);                                              MMA(1, 0, VMNONE);
    RD_B(1, 1);                                              MMA(1, 1, VMNONE);
  }

  // epilogue: route this block's 256 columns to q / k / v region
  size_t obase; int ldc, nc;
  if (n0 < NQ)            { obase = 0;                                        ldc = NQ;  nc = n0; }
  else if (n0 < NQ + NKV) { obase = (size_t)MROWS * NQ;                       ldc = NKV; nc = n0 - NQ; }
  else                    { obase = (size_t)MROWS * NQ + (size_t)MROWS * NKV; ldc = NKV; nc = n0 - NQ - NKV; }

  // C/D layout (verified m74/m101): col = lane&31, row = (reg&3)+8*(reg>>2)+4*hi
#pragma unroll
  for (int I = 0; I < 4; ++I) {
    const int rbase = m0 + (I >> 1) * 128 + wr * 64 + (I & 1) * 32 + hi * 4;
#pragma unroll
    for (int J = 0; J < 2; ++J) {
      const int col = nc + J * 128 + wc * 32 + r32;
#pragma unroll
      for (int reg = 0; reg < 16; ++reg) {
        const int row = rbase + (reg & 3) + 8 * (reg >> 2);
        out[obase + (size_t)row * ldc + col] = acc[I][J][reg];
      }
    }
  }
}

extern "C" void kernel_launch(void* const* d_in, const int* in_sizes, int n_in,
                              void* d_out, int out_size, void* d_ws, size_t ws_size,
                              hipStream_t stream) {
  const float* x     = (const float*)d_in[0];
  const float* gamma = (const float*)d_in[1];
  const float* wq    = (const float*)d_in[2];
  const float* wk    = (const float*)d_in[3];
  const float* wv    = (const float*)d_in[4];
  float* out = (float*)d_out;

  // workspace layout: xn bf16 [8192][4096] then wt bf16 [6144][4096]
  unsigned short* xn = (unsigned short*)d_ws;
  unsigned short* wt = xn + (size_t)MROWS * HD;

  rmsnorm_cast_kernel<<<MROWS, 256, 0, stream>>>(x, gamma, xn);
  transpose_cast_kernel<<<dim3(NQ / 32, HD / 32), 256, 0, stream>>>(wq, wt, NQ);
  transpose_cast_kernel<<<dim3(NKV / 32, HD / 32), 256, 0, stream>>>(
      wk, wt + (size_t)NQ * HD, NKV);
  transpose_cast_kernel<<<dim3(NKV / 32, HD / 32), 256, 0, stream>>>(
      wv, wt + (size_t)(NQ + NKV) * HD, NKV);
  gemm_qkv_kernel<<<(MROWS / 256) * (NTOT / 256), 512, 0, stream>>>(xn, wt, out);
}

// Round 6
// 416.032 us; speedup vs baseline: 1.0873x; 1.0349x over previous
//
#include <hip/hip_runtime.h>
#include <hip/hip_bf16.h>
#include <stdint.h>

// Problem constants (fixed by the reference)
#define HD      4096            // K (hidden)
#define MROWS   8192            // B*S
#define NQ      4096
#define NKV     1024
#define NTOT    6144            // NQ + 2*NKV
#define RMS_EPS 1e-6f

typedef __attribute__((ext_vector_type(8))) short bf16x8;
typedef __attribute__((ext_vector_type(16))) float f32x16;

static __device__ __forceinline__ unsigned short f2bf(float f) {
  union { float f; unsigned u; } a; a.f = f;
  unsigned r = a.u + 0x7FFFu + ((a.u >> 16) & 1u);   // RNE
  return (unsigned short)(r >> 16);
}

// ---------------- RMSNorm + cast to bf16 ----------------
__global__ __launch_bounds__(256) void rmsnorm_cast_kernel(
    const float* __restrict__ x, const float* __restrict__ gamma,
    unsigned short* __restrict__ xn) {
  const int row = blockIdx.x;                 // 8192 rows
  const float4* xr = (const float4*)(x + (size_t)row * HD);
  const float4* g4 = (const float4*)gamma;
  const int t = threadIdx.x;                  // 256 threads
  float4 v[4];
  float ss = 0.f;
#pragma unroll
  for (int i = 0; i < 4; ++i) {
    v[i] = xr[t + i * 256];
    ss += v[i].x * v[i].x + v[i].y * v[i].y + v[i].z * v[i].z + v[i].w * v[i].w;
  }
#pragma unroll
  for (int o = 32; o > 0; o >>= 1) ss += __shfl_xor(ss, o, 64);
  __shared__ float red[4];
  if ((t & 63) == 0) red[t >> 6] = ss;
  __syncthreads();
  const float tot = red[0] + red[1] + red[2] + red[3];
  const float rstd = rsqrtf(tot * (1.f / HD) + RMS_EPS);
  ushort4* xo = (ushort4*)(xn + (size_t)row * HD);
#pragma unroll
  for (int i = 0; i < 4; ++i) {
    const float4 g = g4[t + i * 256];
    ushort4 o;
    o.x = f2bf(v[i].x * rstd * g.x);
    o.y = f2bf(v[i].y * rstd * g.y);
    o.z = f2bf(v[i].z * rstd * g.z);
    o.w = f2bf(v[i].w * rstd * g.w);
    xo[t + i * 256] = o;
  }
}

// ---------------- Transpose + cast W[K][Nw] f32 -> Wt[Nw][K] bf16 ----------------
__global__ __launch_bounds__(256) void transpose_cast_kernel(
    const float* __restrict__ w, unsigned short* __restrict__ wt, int Nw) {
  __shared__ float tile[32][33];
  const int kt = blockIdx.y;                  // K/32
  const int nb = blockIdx.x;                  // Nw/32
  const int t = threadIdx.x;
  const int r = t >> 3, c4 = t & 7;
  const float4 vin = *(const float4*)&w[(size_t)(kt * 32 + r) * Nw + nb * 32 + c4 * 4];
  tile[r][c4 * 4 + 0] = vin.x;
  tile[r][c4 * 4 + 1] = vin.y;
  tile[r][c4 * 4 + 2] = vin.z;
  tile[r][c4 * 4 + 3] = vin.w;
  __syncthreads();
  ushort4 o;
  o.x = f2bf(tile[c4 * 4 + 0][r]);
  o.y = f2bf(tile[c4 * 4 + 1][r]);
  o.z = f2bf(tile[c4 * 4 + 2][r]);
  o.w = f2bf(tile[c4 * 4 + 3][r]);
  *(ushort4*)&wt[(size_t)(nb * 32 + r) * HD + kt * 32 + c4 * 4] = o;
}

// ------- 256x256 single-barrier 8-phase bf16 GEMM, 32x32x16, Gray quadrants ---
// C[M,N] = A[M,K] * Bt[N,K]^T ; M=8192, N=6144, K=4096. BK=64, 512 thr.
//
// Safety ledger (single barrier per phase):
//  * Overwrite: every stage targets a region last READ exactly 2 phases
//    earlier. S(q) issues after BAR(q-1); BAR(q-1) => all waves finished
//    MFMA(q-2), whose lgkm drain retired the R(q-2) reads. Hard-safe.
//  * Landing: vmcnt(4) BEFORE the barrier at p3/p7. Reads needing the
//    drained stages are in later phases (after that barrier for all waves),
//    so every wave's stage slices are complete. p3 drains buf1 (prev p6,p7
//    + p0,p1) before p4; p7 drains next buf0 (p2..p5) before next p0.

static __device__ __forceinline__ void gload_lds16(const unsigned short* g,
                                                   unsigned short* l) {
  __builtin_amdgcn_global_load_lds(
      (const __attribute__((address_space(1))) void*)g,
      (__attribute__((address_space(3))) void*)l, 16, 0, 0);
}

#define VM4 asm volatile("s_waitcnt vmcnt(4)" ::: "memory")
#define VM0 asm volatile("s_waitcnt vmcnt(0)" ::: "memory")

// ds-read the 8 A fragments (2 m-blocks x 4 ks) of row-half HA
#define RD_A(BUF, HA)                                                          \
  do {                                                                         \
    const char* Ah = (const char*)&lds[0][BUF][HA][0];                         \
    _Pragma("unroll") for (int mi = 0; mi < 2; ++mi)                           \
      _Pragma("unroll") for (int ks = 0; ks < 4; ++ks)                         \
        af[mi][ks] = *(const bf16x8*)(Ah + (wr * 64 + mi * 32 + r32) * 128 +   \
                                      (((ks * 2 + hi) ^ swx) << 4));           \
  } while (0)

// ds-read the 4 B fragments (1 n-block x 4 ks) of col-half HB
#define RD_B(BUF, HB)                                                          \
  do {                                                                         \
    const char* Bh = (const char*)&lds[1][BUF][HB][0];                         \
    _Pragma("unroll") for (int ks = 0; ks < 4; ++ks)                           \
      bfr[ks] = *(const bf16x8*)(Bh + (wc * 32 + r32) * 128 +                  \
                                 (((ks * 2 + hi) ^ swx) << 4));                \
  } while (0)

// barrier -> 8 MFMA (quadrant HA x HB over K=64) under setprio. NO 2nd barrier.
#define MMA(HA, HB)                                                            \
  do {                                                                         \
    __builtin_amdgcn_s_barrier();                                              \
    __builtin_amdgcn_s_setprio(1);                                             \
    _Pragma("unroll") for (int ks = 0; ks < 4; ++ks)                           \
      _Pragma("unroll") for (int mi = 0; mi < 2; ++mi)                         \
        acc[(HA) * 2 + mi][HB] = __builtin_amdgcn_mfma_f32_32x32x16_bf16(      \
            af[mi][ks], bfr[ks], acc[(HA) * 2 + mi][HB], 0, 0, 0);             \
    __builtin_amdgcn_s_setprio(0);                                             \
  } while (0)

__global__ __launch_bounds__(512, 2) void gemm_qkv_kernel(
    const unsigned short* __restrict__ A,    // [MROWS][HD] bf16 (xn)
    const unsigned short* __restrict__ Bt,   // [NTOT][HD] bf16 (w^T)
    float* __restrict__ out) {
  // [mat A/B][buf][row-half][128 rows x 64 k] bf16 = 128 KiB total
  __shared__ unsigned short lds[2][2][2][8192] __attribute__((aligned(16)));

  // XCD-rectangular swizzle: grid 32mt x 24nt = 768 blocks, XCD = bid&7.
  const int bid = blockIdx.x;
  const int xcd = bid & 7;
  const int idx = bid >> 3;                  // 0..95
  const int sr  = idx >> 5;                  // sub-round 0..2
  const int i32 = idx & 31;
  const int mt  = (xcd >> 1) * 8 + (i32 >> 2);
  const int nt  = (xcd & 1) * 12 + sr * 4 + (i32 & 3);
  const int m0 = mt * 256, n0 = nt * 256;

  const int tid = threadIdx.x;
  const int w = tid >> 6, lane = tid & 63;
  const int wr = w >> 2, wc = w & 3;         // 2 x 4 waves, each 128x64 out
  const int r32 = lane & 31, hi = lane >> 5; // 32x32 fragment coords
  const int swx = (r32 >> 1) & 7;            // bank swizzle field

  // staging: linear LDS dest, inverse-swizzled global source (rule #21)
  const int wslot = w * 512;                 // wave-uniform LDS element base
  const int r3 = tid >> 3;                   // row 0..63 within pass
  const int scolb = (((tid & 7) ^ ((r3 >> 1) & 7))) << 4;
  const size_t so0 = (size_t)r3 * HD + (scolb >> 1);
  const size_t so1 = so0 + (size_t)64 * HD;

  const unsigned short* const Ab0 = A + (size_t)m0 * HD;
  const unsigned short* const Ab1 = Ab0 + (size_t)128 * HD;
  const unsigned short* const Bb0 = Bt + (size_t)n0 * HD;
  const unsigned short* const Bb1 = Bb0 + (size_t)128 * HD;

  auto STG = [&](const unsigned short* g, unsigned short* l) {
    gload_lds16(g + so0, l + wslot);
    gload_lds16(g + so1, l + 4096 + wslot);
  };

  f32x16 acc[4][2];
#pragma unroll
  for (int i = 0; i < 4; ++i)
#pragma unroll
    for (int j = 0; j < 2; ++j) acc[i][j] = (f32x16)(0.f);

  bf16x8 af[2][4];
  bf16x8 bfr[4];

  // prologue: tile0 -> buf0 (4 regions), tile1 A0/B0 -> buf1
  STG(Ab0, &lds[0][0][0][0]);
  STG(Bb0, &lds[1][0][0][0]);
  STG(Ab1, &lds[0][0][1][0]);
  STG(Bb1, &lds[1][0][1][0]);
  STG(Ab0 + 64, &lds[0][1][0][0]);
  STG(Bb0 + 64, &lds[1][1][0][0]);
  VM4;                                       // tile0's 8 loads landed (pre-bar)
  __builtin_amdgcn_s_barrier();

  // 64 K-tiles, 2 per iter. Reads at use-phase; stages re-spaced to gap-2:
  // p0: b1A1  p1: b1B1  p2: b0A0  p3: b0B0+VM4  p4: b0A1  p5: b0B1
  // p6: b1A0  p7: b1B0+VM4
  for (int t = 0; t < 31; ++t) {
    const size_t k1 = (size_t)(2 * t + 1) * 64;
    const size_t o2 = (size_t)(2 * t + 2) * 64;
    const size_t o3 = (size_t)(2 * t + 3) * 64;
    // ---- buf0 (tile 2t) ----
    RD_A(0, 0); RD_B(0, 1); STG(Ab1 + k1, &lds[0][1][1][0]);      MMA(0, 1); // p0
    RD_B(0, 0);             STG(Bb1 + k1, &lds[1][1][1][0]);      MMA(0, 0); // p1
    RD_A(0, 1);             STG(Ab0 + o2, &lds[0][0][0][0]);      MMA(1, 0); // p2
    RD_B(0, 1);             STG(Bb0 + o2, &lds[1][0][0][0]); VM4; MMA(1, 1); // p3
    // ---- buf1 (tile 2t+1) ----
    RD_A(1, 0); RD_B(1, 1); STG(Ab1 + o2, &lds[0][0][1][0]);      MMA(0, 1); // p4
    RD_B(1, 0);             STG(Bb1 + o2, &lds[1][0][1][0]);      MMA(0, 0); // p5
    RD_A(1, 1);             STG(Ab0 + o3, &lds[0][1][0][0]);      MMA(1, 0); // p6
    RD_B(1, 1);             STG(Bb0 + o3, &lds[1][1][0][0]); VM4; MMA(1, 1); // p7
  }
  {                                          // t = 31: tiles 62 (b0), 63 (b1)
    const size_t k1 = (size_t)63 * 64;
    RD_A(0, 0); RD_B(0, 1); STG(Ab1 + k1, &lds[0][1][1][0]);      MMA(0, 1);
    RD_B(0, 0);             STG(Bb1 + k1, &lds[1][1][1][0]);      MMA(0, 0);
    RD_A(0, 1);                                                   MMA(1, 0);
    RD_B(0, 1);                                              VM0; MMA(1, 1);
    RD_A(1, 0); RD_B(1, 1);                                       MMA(0, 1);
    RD_B(1, 0);                                                   MMA(0, 0);
    RD_A(1, 1);                                                   MMA(1, 0);
    RD_B(1, 1);                                                   MMA(1, 1);
  }

  // epilogue: route this block's 256 columns to q / k / v region
  size_t obase; int ldc, nc;
  if (n0 < NQ)            { obase = 0;                                        ldc = NQ;  nc = n0; }
  else if (n0 < NQ + NKV) { obase = (size_t)MROWS * NQ;                       ldc = NKV; nc = n0 - NQ; }
  else                    { obase = (size_t)MROWS * NQ + (size_t)MROWS * NKV; ldc = NKV; nc = n0 - NQ - NKV; }

  // C/D layout (verified m74/m101): col = lane&31, row = (reg&3)+8*(reg>>2)+4*hi
#pragma unroll
  for (int I = 0; I < 4; ++I) {
    const int rbase = m0 + (I >> 1) * 128 + wr * 64 + (I & 1) * 32 + hi * 4;
#pragma unroll
    for (int J = 0; J < 2; ++J) {
      const int col = nc + J * 128 + wc * 32 + r32;
#pragma unroll
      for (int reg = 0; reg < 16; ++reg) {
        const int row = rbase + (reg & 3) + 8 * (reg >> 2);
        out[obase + (size_t)row * ldc + col] = acc[I][J][reg];
      }
    }
  }
}

extern "C" void kernel_launch(void* const* d_in, const int* in_sizes, int n_in,
                              void* d_out, int out_size, void* d_ws, size_t ws_size,
                              hipStream_t stream) {
  const float* x     = (const float*)d_in[0];
  const float* gamma = (const float*)d_in[1];
  const float* wq    = (const float*)d_in[2];
  const float* wk    = (const float*)d_in[3];
  const float* wv    = (const float*)d_in[4];
  float* out = (float*)d_out;

  // workspace layout: xn bf16 [8192][4096] then wt bf16 [6144][4096]
  unsigned short* xn = (unsigned short*)d_ws;
  unsigned short* wt = xn + (size_t)MROWS * HD;

  rmsnorm_cast_kernel<<<MROWS, 256, 0, stream>>>(x, gamma, xn);
  transpose_cast_kernel<<<dim3(NQ / 32, HD / 32), 256, 0, stream>>>(wq, wt, NQ);
  transpose_cast_kernel<<<dim3(NKV / 32, HD / 32), 256, 0, stream>>>(
      wk, wt + (size_t)NQ * HD, NKV);
  transpose_cast_kernel<<<dim3(NKV / 32, HD / 32), 256, 0, stream>>>(
      wv, wt + (size_t)(NQ + NKV) * HD, NKV);
  gemm_qkv_kernel<<<(MROWS / 256) * (NTOT / 256), 512, 0, stream>>>(xn, wt, out);
}

// Round 7
// 413.514 us; speedup vs baseline: 1.0939x; 1.0061x over previous
//
#include <hip/hip_runtime.h>
#include <hip/hip_bf16.h>
#include <stdint.h>

// Problem constants (fixed by the reference)
#define HD      4096            // K (hidden)
#define MROWS   8192            // B*S
#define NQ      4096
#define NKV     1024
#define NTOT    6144            // NQ + 2*NKV
#define RMS_EPS 1e-6f

typedef __attribute__((ext_vector_type(8))) short bf16x8;
typedef __attribute__((ext_vector_type(16))) float f32x16;

static __device__ __forceinline__ unsigned short f2bf(float f) {
  union { float f; unsigned u; } a; a.f = f;
  unsigned r = a.u + 0x7FFFu + ((a.u >> 16) & 1u);   // RNE
  return (unsigned short)(r >> 16);
}

// ---------------- RMSNorm + cast to bf16 ----------------
__global__ __launch_bounds__(256) void rmsnorm_cast_kernel(
    const float* __restrict__ x, const float* __restrict__ gamma,
    unsigned short* __restrict__ xn) {
  const int row = blockIdx.x;                 // 8192 rows
  const float4* xr = (const float4*)(x + (size_t)row * HD);
  const float4* g4 = (const float4*)gamma;
  const int t = threadIdx.x;                  // 256 threads
  float4 v[4];
  float ss = 0.f;
#pragma unroll
  for (int i = 0; i < 4; ++i) {
    v[i] = xr[t + i * 256];
    ss += v[i].x * v[i].x + v[i].y * v[i].y + v[i].z * v[i].z + v[i].w * v[i].w;
  }
#pragma unroll
  for (int o = 32; o > 0; o >>= 1) ss += __shfl_xor(ss, o, 64);
  __shared__ float red[4];
  if ((t & 63) == 0) red[t >> 6] = ss;
  __syncthreads();
  const float tot = red[0] + red[1] + red[2] + red[3];
  const float rstd = rsqrtf(tot * (1.f / HD) + RMS_EPS);
  ushort4* xo = (ushort4*)(xn + (size_t)row * HD);
#pragma unroll
  for (int i = 0; i < 4; ++i) {
    const float4 g = g4[t + i * 256];
    ushort4 o;
    o.x = f2bf(v[i].x * rstd * g.x);
    o.y = f2bf(v[i].y * rstd * g.y);
    o.z = f2bf(v[i].z * rstd * g.z);
    o.w = f2bf(v[i].w * rstd * g.w);
    xo[t + i * 256] = o;
  }
}

// ---------------- Transpose + cast W[K][Nw] f32 -> Wt[Nw][K] bf16 ----------------
__global__ __launch_bounds__(256) void transpose_cast_kernel(
    const float* __restrict__ w, unsigned short* __restrict__ wt, int Nw) {
  __shared__ float tile[32][33];
  const int kt = blockIdx.y;                  // K/32
  const int nb = blockIdx.x;                  // Nw/32
  const int t = threadIdx.x;
  const int r = t >> 3, c4 = t & 7;
  const float4 vin = *(const float4*)&w[(size_t)(kt * 32 + r) * Nw + nb * 32 + c4 * 4];
  tile[r][c4 * 4 + 0] = vin.x;
  tile[r][c4 * 4 + 1] = vin.y;
  tile[r][c4 * 4 + 2] = vin.z;
  tile[r][c4 * 4 + 3] = vin.w;
  __syncthreads();
  ushort4 o;
  o.x = f2bf(tile[c4 * 4 + 0][r]);
  o.y = f2bf(tile[c4 * 4 + 1][r]);
  o.z = f2bf(tile[c4 * 4 + 2][r]);
  o.w = f2bf(tile[c4 * 4 + 3][r]);
  *(ushort4*)&wt[(size_t)(nb * 32 + r) * HD + kt * 32 + c4 * 4] = o;
}

// -- 256x256 half-cluster-pipelined bf16 GEMM, 32x32x16, Gray quadrants --------
// C[M,N] = A[M,K] * Bt[N,K]^T ; M=8192, N=6144, K=4096. BK=64, 512 thr.
//
// Window q = [bar; R(q.1)->{af1,bf1}; STG; M(q.0)<-{af0,bf0}; R(q+1.0)->{af0,bf0};
//            M(q.1)<-{af1,bf1}; (VM)].
// R(q.1) overlaps M(q.0) (no dep); R(q+1.0)'s WAR on {af0,bf0} releases when
// M(q.0) retires, hidden under M(q.1). Frag regs stay at 48 VGPR (no dbuf).
//
// Stage ledger (1 stage/window; region -> phases -> read windows [late=R(.0),
// early=R(.1)]):
//   b0AH0 p0,p1 reads w7'/w0 | staged w1  (o2)  drain VM4@w6 < read w7 OK
//   b0AH1 p2,p3 reads w1/w2  | staged w3  (o2)  drain VM4@w6 < read w1' OK
//   b1AH0 p4,p5 reads w3/w4  | staged w5  (o3)  drain VM4@w2' < read w3' OK
//   b1AH1 p6,p7 reads w5/w6  | staged w7  (o3)  drain VM4@w2' < read w5' OK
//   b0BH0 p1,p2 reads w0/w1  | staged w2  (o2)  drain VM4@w6 < read w0' OK
//   b0BH1 p0,p3 reads w7'/w0 + w2/w3 | staged w4 (o2) drain VM4@w6 < read w7 OK
//   b1BH0 p5,p6 reads w4/w5  | staged w6  (o3)  drain VM4@w2' < read w4' OK
//   b1BH1 p4,p7 reads w3/w4 + w6/w7 | staged w0 (k1) drain VM4@w2 < read w3 OK
// Overwrite: every stage s >= (last-read drain barrier) -- verified per region.
// VM4@w2: outstanding {w5',w6',w7',w0,w1,w2}=12 -> drains thru w0 (2-win old).
// VM4@w6: outstanding {w1,w2,w3,w4,w5,w6}=12 -> drains thru w4 (2-win old).

static __device__ __forceinline__ void gload_lds16(const unsigned short* g,
                                                   unsigned short* l) {
  __builtin_amdgcn_global_load_lds(
      (const __attribute__((address_space(1))) void*)g,
      (__attribute__((address_space(3))) void*)l, 16, 0, 0);
}

#define VM4 asm volatile("s_waitcnt vmcnt(4)" ::: "memory")
#define VM6 asm volatile("s_waitcnt vmcnt(6)" ::: "memory")
#define VM0 asm volatile("s_waitcnt vmcnt(0)" ::: "memory")
#define BAR __builtin_amdgcn_s_barrier()

// A-fragment half reads: ks pair {0,1} -> af0, {2,3} -> af1
#define RA0(BUF, HA)                                                           \
  do {                                                                         \
    const char* Ah = (const char*)&lds[0][BUF][HA][0];                         \
    _Pragma("unroll") for (int mi = 0; mi < 2; ++mi)                           \
      _Pragma("unroll") for (int k = 0; k < 2; ++k)                            \
        af0[mi][k] = *(const bf16x8*)(Ah + (wr * 64 + mi * 32 + r32) * 128 +   \
                                      (((k * 2 + hi) ^ swx) << 4));            \
  } while (0)
#define RA1(BUF, HA)                                                           \
  do {                                                                         \
    const char* Ah = (const char*)&lds[0][BUF][HA][0];                         \
    _Pragma("unroll") for (int mi = 0; mi < 2; ++mi)                           \
      _Pragma("unroll") for (int k = 0; k < 2; ++k)                            \
        af1[mi][k] = *(const bf16x8*)(Ah + (wr * 64 + mi * 32 + r32) * 128 +   \
                                      ((((k + 2) * 2 + hi) ^ swx) << 4));      \
  } while (0)
#define RB0(BUF, HB)                                                           \
  do {                                                                         \
    const char* Bh = (const char*)&lds[1][BUF][HB][0];                         \
    _Pragma("unroll") for (int k = 0; k < 2; ++k)                              \
      bf0[k] = *(const bf16x8*)(Bh + (wc * 32 + r32) * 128 +                   \
                                (((k * 2 + hi) ^ swx) << 4));                  \
  } while (0)
#define RB1(BUF, HB)                                                           \
  do {                                                                         \
    const char* Bh = (const char*)&lds[1][BUF][HB][0];                         \
    _Pragma("unroll") for (int k = 0; k < 2; ++k)                              \
      bf1[k] = *(const bf16x8*)(Bh + (wc * 32 + r32) * 128 +                   \
                                ((((k + 2) * 2 + hi) ^ swx) << 4));            \
  } while (0)

// MFMA half-clusters (4 each) for quadrant (HA,HB)
#define M0(HA, HB)                                                             \
  do {                                                                         \
    __builtin_amdgcn_s_setprio(1);                                             \
    _Pragma("unroll") for (int k = 0; k < 2; ++k)                              \
      _Pragma("unroll") for (int mi = 0; mi < 2; ++mi)                         \
        acc[(HA) * 2 + mi][HB] = __builtin_amdgcn_mfma_f32_32x32x16_bf16(      \
            af0[mi][k], bf0[k], acc[(HA) * 2 + mi][HB], 0, 0, 0);              \
    __builtin_amdgcn_s_setprio(0);                                             \
  } while (0)
#define M1(HA, HB)                                                             \
  do {                                                                         \
    __builtin_amdgcn_s_setprio(1);                                             \
    _Pragma("unroll") for (int k = 0; k < 2; ++k)                              \
      _Pragma("unroll") for (int mi = 0; mi < 2; ++mi)                         \
        acc[(HA) * 2 + mi][HB] = __builtin_amdgcn_mfma_f32_32x32x16_bf16(      \
            af1[mi][k], bf1[k], acc[(HA) * 2 + mi][HB], 0, 0, 0);              \
    __builtin_amdgcn_s_setprio(0);                                             \
  } while (0)

__global__ __launch_bounds__(512, 2) void gemm_qkv_kernel(
    const unsigned short* __restrict__ A,    // [MROWS][HD] bf16 (xn)
    const unsigned short* __restrict__ Bt,   // [NTOT][HD] bf16 (w^T)
    float* __restrict__ out) {
  // [mat A/B][buf][row-half][128 rows x 64 k] bf16 = 128 KiB total
  __shared__ unsigned short lds[2][2][2][8192] __attribute__((aligned(16)));

  // XCD-rectangular swizzle: grid 32mt x 24nt = 768 blocks, XCD = bid&7.
  const int bid = blockIdx.x;
  const int xcd = bid & 7;
  const int idx = bid >> 3;                  // 0..95
  const int sr  = idx >> 5;                  // sub-round 0..2
  const int i32 = idx & 31;
  const int mt  = (xcd >> 1) * 8 + (i32 >> 2);
  const int nt  = (xcd & 1) * 12 + sr * 4 + (i32 & 3);
  const int m0 = mt * 256, n0 = nt * 256;

  const int tid = threadIdx.x;
  const int w = tid >> 6, lane = tid & 63;
  const int wr = w >> 2, wc = w & 3;         // 2 x 4 waves, each 128x64 out
  const int r32 = lane & 31, hi = lane >> 5; // 32x32 fragment coords
  const int swx = (r32 >> 1) & 7;            // bank swizzle field

  // staging: linear LDS dest, inverse-swizzled global source (rule #21)
  const int wslot = w * 512;                 // wave-uniform LDS element base
  const int r3 = tid >> 3;                   // row 0..63 within pass
  const int scolb = (((tid & 7) ^ ((r3 >> 1) & 7))) << 4;
  const size_t so0 = (size_t)r3 * HD + (scolb >> 1);
  const size_t so1 = so0 + (size_t)64 * HD;

  const unsigned short* const Ab0 = A + (size_t)m0 * HD;
  const unsigned short* const Ab1 = Ab0 + (size_t)128 * HD;
  const unsigned short* const Bb0 = Bt + (size_t)n0 * HD;
  const unsigned short* const Bb1 = Bb0 + (size_t)128 * HD;

  auto STG = [&](const unsigned short* g, unsigned short* l) {
    gload_lds16(g + so0, l + wslot);
    gload_lds16(g + so1, l + 4096 + wslot);
  };

  f32x16 acc[4][2];
#pragma unroll
  for (int i = 0; i < 4; ++i)
#pragma unroll
    for (int j = 0; j < 2; ++j) acc[i][j] = (f32x16)(0.f);

  bf16x8 af0[2][2], af1[2][2];
  bf16x8 bf0[2], bf1[2];

  // prologue: stage tile0 (buf0: AH0, BH1, AH1, BH0) then tile1 (AH0, BH0, AH1)
  STG(Ab0,      &lds[0][0][0][0]);           // 1 b0 A H0
  STG(Bb1,      &lds[1][0][1][0]);           // 2 b0 B H1
  STG(Ab1,      &lds[0][0][1][0]);           // 3 b0 A H1
  STG(Bb0,      &lds[1][0][0][0]);           // 4 b0 B H0
  STG(Ab0 + 64, &lds[0][1][0][0]);           // 5 b1 A H0
  STG(Bb0 + 64, &lds[1][1][0][0]);           // 6 b1 B H0
  STG(Ab1 + 64, &lds[0][1][1][0]);           // 7 b1 A H1
  VM6;                                       // drains 1-4 (all of buf0)
  BAR;
  RA0(0, 0); RB0(0, 1);                      // R(p0.0)

  for (int t = 0; t < 31; ++t) {
    const size_t k1 = (size_t)(2 * t + 1) * 64;
    const size_t o2 = (size_t)(2 * t + 2) * 64;
    const size_t o3 = (size_t)(2 * t + 3) * 64;
    // w0 (p0 = buf0 quad (0,1))
    RA1(0, 0); RB1(0, 1); STG(Bb1 + k1, &lds[1][1][1][0]);
    M0(0, 1); RB0(0, 0); M1(0, 1); BAR;
    // w1 (p1 = (0,0))
    RB1(0, 0); STG(Ab0 + o2, &lds[0][0][0][0]);
    M0(0, 0); RA0(0, 1); M1(0, 0); BAR;
    // w2 (p2 = (1,0))
    RA1(0, 1); STG(Bb0 + o2, &lds[1][0][0][0]);
    M0(1, 0); RB0(0, 1); M1(1, 0); VM4; BAR;
    // w3 (p3 = (1,1))
    RB1(0, 1); STG(Ab1 + o2, &lds[0][0][1][0]);
    M0(1, 1); RA0(1, 0); RB0(1, 1); M1(1, 1); BAR;
    // w4 (p4 = buf1 quad (0,1))
    RA1(1, 0); RB1(1, 1); STG(Bb1 + o2, &lds[1][0][1][0]);
    M0(0, 1); RB0(1, 0); M1(0, 1); BAR;
    // w5 (p5 = (0,0))
    RB1(1, 0); STG(Ab0 + o3, &lds[0][1][0][0]);
    M0(0, 0); RA0(1, 1); M1(0, 0); BAR;
    // w6 (p6 = (1,0))
    RA1(1, 1); STG(Bb0 + o3, &lds[1][1][0][0]);
    M0(1, 0); RB0(1, 1); M1(1, 0); VM4; BAR;
    // w7 (p7 = (1,1))
    RB1(1, 1); STG(Ab1 + o3, &lds[0][1][1][0]);
    M0(1, 1); RA0(0, 0); RB0(0, 1); M1(1, 1); BAR;
  }
  {                                          // t = 31: tiles 62 (b0), 63 (b1)
    const size_t k1 = (size_t)63 * 64;
    RA1(0, 0); RB1(0, 1); STG(Bb1 + k1, &lds[1][1][1][0]);
    M0(0, 1); RB0(0, 0); M1(0, 1); BAR;
    RB1(0, 0); M0(0, 0); RA0(0, 1); M1(0, 0); BAR;
    RA1(0, 1); M0(1, 0); RB0(0, 1); M1(1, 0); VM0; BAR;
    RB1(0, 1); M0(1, 1); RA0(1, 0); RB0(1, 1); M1(1, 1); BAR;
    RA1(1, 0); RB1(1, 1); M0(0, 1); RB0(1, 0); M1(0, 1); BAR;
    RB1(1, 0); M0(0, 0); RA0(1, 1); M1(0, 0); BAR;
    RA1(1, 1); M0(1, 0); RB0(1, 1); M1(1, 0); BAR;
    RB1(1, 1); M0(1, 1); M1(1, 1);
  }

  // epilogue: route this block's 256 columns to q / k / v region
  size_t obase; int ldc, nc;
  if (n0 < NQ)            { obase = 0;                                        ldc = NQ;  nc = n0; }
  else if (n0 < NQ + NKV) { obase = (size_t)MROWS * NQ;                       ldc = NKV; nc = n0 - NQ; }
  else                    { obase = (size_t)MROWS * NQ + (size_t)MROWS * NKV; ldc = NKV; nc = n0 - NQ - NKV; }

  // C/D layout (verified m74/m101): col = lane&31, row = (reg&3)+8*(reg>>2)+4*hi
#pragma unroll
  for (int I = 0; I < 4; ++I) {
    const int rbase = m0 + (I >> 1) * 128 + wr * 64 + (I & 1) * 32 + hi * 4;
#pragma unroll
    for (int J = 0; J < 2; ++J) {
      const int col = nc + J * 128 + wc * 32 + r32;
#pragma unroll
      for (int reg = 0; reg < 16; ++reg) {
        const int row = rbase + (reg & 3) + 8 * (reg >> 2);
        out[obase + (size_t)row * ldc + col] = acc[I][J][reg];
      }
    }
  }
}

extern "C" void kernel_launch(void* const* d_in, const int* in_sizes, int n_in,
                              void* d_out, int out_size, void* d_ws, size_t ws_size,
                              hipStream_t stream) {
  const float* x     = (const float*)d_in[0];
  const float* gamma = (const float*)d_in[1];
  const float* wq    = (const float*)d_in[2];
  const float* wk    = (const float*)d_in[3];
  const float* wv    = (const float*)d_in[4];
  float* out = (float*)d_out;

  // workspace layout: xn bf16 [8192][4096] then wt bf16 [6144][4096]
  unsigned short* xn = (unsigned short*)d_ws;
  unsigned short* wt = xn + (size_t)MROWS * HD;

  rmsnorm_cast_kernel<<<MROWS, 256, 0, stream>>>(x, gamma, xn);
  transpose_cast_kernel<<<dim3(NQ / 32, HD / 32), 256, 0, stream>>>(wq, wt, NQ);
  transpose_cast_kernel<<<dim3(NKV / 32, HD / 32), 256, 0, stream>>>(
      wk, wt + (size_t)NQ * HD, NKV);
  transpose_cast_kernel<<<dim3(NKV / 32, HD / 32), 256, 0, stream>>>(
      wv, wt + (size_t)(NQ + NKV) * HD, NKV);
  gemm_qkv_kernel<<<(MROWS / 256) * (NTOT / 256), 512, 0, stream>>>(xn, wt, out);
}